// Round 1
// baseline (269.694 us; speedup 1.0000x reference)
//
#include <hip/hip_runtime.h>

// out[t,b,i,e] = x[t,b,i] * W[i,e] + b[e]
// T=8, B=64, D=512, E=256, fp32. Output 256 MiB -> pure write-stream kernel.
//
// v2 changes vs v1 (269 us session best):
//  - PLAIN stores instead of nontemporal: the harness's own fillBuffer hits
//    6.34 TB/s with plain dwordx4 stores on a 1 GiB buffer, proving nt is not
//    needed for a write-once stream (and may cost combining efficiency).
//  - 32 B/lane/iter (two consecutive dwordx4): each wave writes a 2 KiB
//    contiguous burst (full rows i and i+1), 2 independent stores per x load.
//
// Thread owns (i, e8) where e8 indexes an 8-float chunk of E:
//   - W[i][e8*8..+7] and b[e8*8..+7] register-resident for the whole kernel.
//   - Loop over 16 of the 512 (t,b) rows: half-wave-uniform x load, 8 FMAs,
//     two coalesced dwordx4 stores -> 2 KiB/wave contiguous burst.
// 32 slices x 512 i x 32 e8 = 524288 threads = 2048 blocks of 256
//   = 8192 waves = exactly 256 CU x 32 waves/CU.

#define DD     512                 // D
#define E4     64                  // E/4 (float4 granularity of a row)
#define NROW   512                 // T*B
#define RPT    16                  // rows per thread
#define SLICES (NROW / RPT)        // 32

__global__ __launch_bounds__(256) void dense_embed_kernel(
    const float*  __restrict__ x,    // (NROW, D)
    const float4* __restrict__ W,    // (D, E4)
    const float4* __restrict__ b,    // (E4)
    float4*       __restrict__ out)  // (NROW*D, E4)
{
    const int gtid  = blockIdx.x * 256 + threadIdx.x;
    const int e8    = gtid & 31;             // 8-float chunk of E: lanes 0..31
    const int i     = (gtid >> 5) & (DD - 1);// row of W; wave covers i, i+1
    const int slice = gtid >> 14;            // 0..31

    // Register-resident weight/bias chunk (32 B each).
    const int wi = (i << 6) | (e8 << 1);
    const float4 w0  = W[wi];
    const float4 w1  = W[wi | 1];
    const float4 bb0 = b[e8 << 1];
    const float4 bb1 = b[(e8 << 1) | 1];

    const int r0 = slice * RPT;
    const float* xp = x + (size_t)r0 * DD + i;                  // half-wave-uniform
    float4* op = out + (((size_t)r0 * DD + i) << 6) + (e8 << 1);// lane-consecutive, 32 B/lane

    #pragma unroll 4
    for (int k = 0; k < RPT; ++k) {
        const float xv = *xp;                // broadcast within half-wave
        float4 o0, o1;
        o0.x = fmaf(xv, w0.x, bb0.x);
        o0.y = fmaf(xv, w0.y, bb0.y);
        o0.z = fmaf(xv, w0.z, bb0.z);
        o0.w = fmaf(xv, w0.w, bb0.w);
        o1.x = fmaf(xv, w1.x, bb1.x);
        o1.y = fmaf(xv, w1.y, bb1.y);
        o1.z = fmaf(xv, w1.z, bb1.z);
        o1.w = fmaf(xv, w1.w, bb1.w);
        op[0] = o0;                          // global_store_dwordx4 (plain)
        op[1] = o1;                          // 2 KiB contiguous per wave
        xp += DD;                            // next (t,b) row, same i
        op += (size_t)DD * E4;
    }
}

extern "C" void kernel_launch(void* const* d_in, const int* in_sizes, int n_in,
                              void* d_out, int out_size, void* d_ws, size_t ws_size,
                              hipStream_t stream) {
    const float*  x = (const float*)d_in[0];
    const float4* W = (const float4*)d_in[1];
    const float4* b = (const float4*)d_in[2];
    float4* out = (float4*)d_out;

    dense_embed_kernel<<<2048, 256, 0, stream>>>(x, W, b, out);
}

// Round 2
// 269.311 us; speedup vs baseline: 1.0014x; 1.0014x over previous
//
#include <hip/hip_runtime.h>

// out[t,b,i,e] = x[t,b,i] * W[i,e] + b[e]
// T=8, B=64, D=512, E=256, fp32. Output 256 MiB -> pure write-stream kernel.
//
// v3: store stream shaped EXACTLY like the harness's fillBuffer (which hits
// 6.6 TB/s on a 1 GiB buffer in the same capture): flat grid-stride over the
// output as float4s -> the whole grid writes one contiguous 8 MiB span per
// step and marches linearly through the 256 MiB buffer (single write front),
// instead of v1/v2's 32 separated slice-fronts with 512 KiB wave jumps.
//
// The grid-stride decode degenerates to constants per thread:
//   f = idx + k*2^19  (2048*256 threads = 2^19 float4s/step, 32 steps)
//   e4 = f&63   = idx&63        (const)  -> b[e4]  register-resident
//   i  = (f>>6)&511 = const               -> W[i,e4] register-resident
//   r  = f>>15  = (idx>>15) + 16k         -> x walks 16 rows/step
// Per iter: 1 wave-uniform x load (one addr/wave, broadcast), 4 FMAs,
// 1 plain global_store_dwordx4. 8192 waves = full 32-wave/CU residency.

#define DD       512                  // D
#define E4       64                   // E/4
#define NROW     512                  // T*B
#define NTHREADS (2048 * 256)         // 2^19 threads = f4s per grid step
#define NF4      (NROW * DD * E4)     // 2^24 total output float4s
#define ITERS    (NF4 / NTHREADS)     // 32

__global__ __launch_bounds__(256) void dense_embed_kernel(
    const float*  __restrict__ x,    // (NROW, D)
    const float4* __restrict__ W,    // (D, E4)
    const float4* __restrict__ b,    // (E4)
    float4*       __restrict__ out)  // flat (NF4)
{
    const int idx = blockIdx.x * 256 + threadIdx.x;  // f4 index at step 0
    const int e4  = idx & (E4 - 1);                  // const per thread
    const int i   = (idx >> 6) & (DD - 1);           // const per thread
    const int r0  = idx >> 15;                       // 0..15

    const float4 w  = W[(i << 6) | e4];              // register-resident
    const float4 bb = b[e4];

    const float* xp = x + (size_t)r0 * DD + i;       // wave-uniform addr
    float4*      op = out + idx;                     // grid-linear

    #pragma unroll 8
    for (int k = 0; k < ITERS; ++k) {
        const float xv = *xp;                        // broadcast within wave
        float4 o;
        o.x = fmaf(xv, w.x, bb.x);
        o.y = fmaf(xv, w.y, bb.y);
        o.z = fmaf(xv, w.z, bb.z);
        o.w = fmaf(xv, w.w, bb.w);
        *op = o;                                     // plain dwordx4, fill-shaped
        xp += 16 * DD;                               // r advances by 16 rows/step
        op += NTHREADS;                              // next 8 MiB span
    }
}

extern "C" void kernel_launch(void* const* d_in, const int* in_sizes, int n_in,
                              void* d_out, int out_size, void* d_ws, size_t ws_size,
                              hipStream_t stream) {
    const float*  x = (const float*)d_in[0];
    const float4* W = (const float4*)d_in[1];
    const float4* b = (const float4*)d_in[2];
    float4* out = (float4*)d_out;

    dense_embed_kernel<<<2048, 256, 0, stream>>>(x, W, b, out);
}